// Round 1
// baseline (383.584 us; speedup 1.0000x reference)
//
#include <hip/hip_runtime.h>
#include <stdint.h>

#define Bn 2
#define Hn 4
#define Tn 2048
#define Nn 2048
#define Dn 256
#define BH (Bn * Hn)
#define NT 16        // 128-row t-tiles per head
#define Gs 4         // s-tiles per block
#define JPH 40       // sum over tt of ceil((tt+1)/Gs)

typedef __attribute__((ext_vector_type(8))) short short8;
typedef __attribute__((ext_vector_type(4))) float f32x4;

__device__ __forceinline__ uint16_t f2bf(float x) {
  uint32_t u = __float_as_uint(x);
  return (uint16_t)((u + 0x7FFFu + ((u >> 16) & 1u)) >> 16);   // RNE, no NaNs in data
}

__device__ __forceinline__ void gload_lds16(const void* g, void* l) {
  __builtin_amdgcn_global_load_lds((const __attribute__((address_space(1))) uint32_t*)g,
                                   (__attribute__((address_space(3))) uint32_t*)l,
                                   16, 0, 0);
}

// ---------------- RoPE + bf16 cast: QR[bh][t][n] ----------------
__global__ void rope_kernel(const float* __restrict__ Q, uint16_t* __restrict__ QR) {
  size_t v = (size_t)blockIdx.x * blockDim.x + threadIdx.x;  // one thread per 4 elems (2 pairs)
  size_t e = v * 4;
  int n = (int)(e & (Nn - 1));
  int t = (int)((e >> 11) & (Tn - 1));
  const float4 q = *(const float4*)(Q + e);
  int p0 = n >> 1;
  // freq = THETA^(-2p/N)/(2pi) = exp2(-p/64) * (1/2pi)
  float f0 = exp2f(-(float)p0 * (1.0f / 64.0f)) * 0.15915494309189535f;
  float f1 = exp2f(-(float)(p0 + 1) * (1.0f / 64.0f)) * 0.15915494309189535f;
  float x0 = (float)t * f0, x1 = (float)t * f1;
  float r0 = x0 - floorf(x0), r1 = x1 - floorf(x1);          // revolutions in [0,1)
  float s0 = __builtin_amdgcn_sinf(r0), c0 = __builtin_amdgcn_cosf(r0);  // sin/cos(2*pi*x)
  float s1 = __builtin_amdgcn_sinf(r1), c1 = __builtin_amdgcn_cosf(r1);
  float o0 = q.x * c0 - q.y * s0;
  float o1 = q.y * c0 + q.x * s0;
  float o2 = q.z * c1 - q.w * s1;
  float o3 = q.w * c1 + q.z * s1;
  uint32_t lo = (uint32_t)f2bf(o0) | ((uint32_t)f2bf(o1) << 16);
  uint32_t hi = (uint32_t)f2bf(o2) | ((uint32_t)f2bf(o3) << 16);
  *(uint2*)(QR + e) = make_uint2(lo, hi);
}

// ---------------- V transpose to bf16: VT[b][d][t] ----------------
__global__ void vt_kernel(const float* __restrict__ V, uint16_t* __restrict__ VT) {
  int o = blockIdx.x * 256 + threadIdx.x;                    // < 2^20
  int t = o & (Tn - 1);
  int d = (o >> 11) & (Dn - 1);
  int b = o >> 19;
  VT[o] = f2bf(V[((size_t)b * Tn + t) * Dn + d]);
}

// ---------------- masked QK^T * V, bf16 MFMA ----------------
__global__ __launch_bounds__(512) void attn_kernel(const uint16_t* __restrict__ QR,
                                                   const uint16_t* __restrict__ VT,
                                                   float* __restrict__ O) {
  int bx = blockIdx.x;
  int bh = bx / JPH;
  int r = bx - bh * JPH;
  int tt = 0;
  for (; tt < NT; ++tt) {
    int nj = (tt + Gs) / Gs;     // ceil((tt+1)/Gs)
    if (r < nj) break;
    r -= nj;
  }
  const int s0 = r * Gs;
  const int sEnd = min(s0 + Gs, tt + 1);
  const int b = bh >> 2;         // H = 4

  const int tid = threadIdx.x;
  const int w = tid >> 6;
  const int l = tid & 63;
  const int l15 = l & 15;
  const int lg = l >> 4;

  // QK wave grid over ST (128 j x 128 i): 2 x 4
  const int wj = w >> 2;         // j block of 64
  const int wi = w & 3;          // i block of 32
  // PV wave grid over OT (256 d x 128 i): 4 x 2
  const int wd = w >> 1;         // d block of 64
  const int wi2 = w & 1;         // i block of 64

  __shared__ __align__(16) uint16_t Qt[128 * 64];   // [i-row][k] chunk-swizzled
  __shared__ __align__(16) uint16_t Qs[128 * 64];   // [j-row][k] chunk-swizzled
  __shared__ __align__(16) uint16_t Sl[128 * 128];  // [i][j] bf16, chunk-swizzled by i&15

  const uint16_t* QRh = QR + (size_t)bh * Tn * Nn;

  const f32x4 zero = {0.f, 0.f, 0.f, 0.f};
  f32x4 oacc[4][4];
#pragma unroll
  for (int m = 0; m < 4; ++m)
#pragma unroll
    for (int n = 0; n < 4; ++n) oacc[m][n] = zero;

  // staging slot for this thread (linear LDS dest, inverse-swizzled source)
  const int srow = tid >> 3;                 // 0..63
  const int scg = (tid & 7) ^ (srow & 7);    // swizzled source 16B-chunk

  char* QtB = (char*)Qt;
  char* QsB = (char*)Qs;
  char* SlB = (char*)Sl;

  for (int st = s0; st < sEnd; ++st) {
    f32x4 sacc[4][2];
#pragma unroll
    for (int m = 0; m < 4; ++m) { sacc[m][0] = zero; sacc[m][1] = zero; }

    const uint16_t* gQt0 = QRh + (size_t)(tt * 128 + srow) * Nn + scg * 8;
    const uint16_t* gQt1 = QRh + (size_t)(tt * 128 + 64 + srow) * Nn + scg * 8;
    const uint16_t* gQs0 = QRh + (size_t)(st * 128 + srow) * Nn + scg * 8;
    const uint16_t* gQs1 = QRh + (size_t)(st * 128 + 64 + srow) * Nn + scg * 8;

    for (int k0 = 0; k0 < Nn; k0 += 64) {
      __syncthreads();
      gload_lds16(gQt0 + k0, QtB + w * 1024);
      gload_lds16(gQt1 + k0, QtB + 8192 + w * 1024);
      gload_lds16(gQs0 + k0, QsB + w * 1024);
      gload_lds16(gQs1 + k0, QsB + 8192 + w * 1024);
      __syncthreads();
#pragma unroll
      for (int ks = 0; ks < 2; ++ks) {
        short8 a[4], bb[2];
#pragma unroll
        for (int m = 0; m < 4; ++m) {
          int row = wj * 64 + m * 16 + l15;                       // j row
          int c = (4 * ks + lg) ^ (row & 7);
          a[m] = *(const short8*)(QsB + row * 128 + c * 16);
        }
#pragma unroll
        for (int n = 0; n < 2; ++n) {
          int row = wi * 32 + n * 16 + l15;                       // i row
          int c = (4 * ks + lg) ^ (row & 7);
          bb[n] = *(const short8*)(QtB + row * 128 + c * 16);
        }
#pragma unroll
        for (int m = 0; m < 4; ++m)
#pragma unroll
          for (int n = 0; n < 2; ++n)
            sacc[m][n] = __builtin_amdgcn_mfma_f32_16x16x32_bf16(a[m], bb[n], sacc[m][n], 0, 0, 0);
      }
    }

    // mask (strict causal: keep j < i on diagonal tile) + pack ST -> Sl[i][j]
    const bool diag = (st == tt);
#pragma unroll
    for (int m = 0; m < 4; ++m)
#pragma unroll
      for (int n = 0; n < 2; ++n) {
        int j0 = wj * 64 + m * 16 + lg * 4;    // 4 consecutive j (C/D rows)
        int i = wi * 32 + n * 16 + l15;        // C/D col
        f32x4 v = sacc[m][n];
        if (diag) {
#pragma unroll
          for (int rr = 0; rr < 4; ++rr)
            if (j0 + rr >= i) v[rr] = 0.f;
        }
        uint32_t lo = (uint32_t)f2bf(v[0]) | ((uint32_t)f2bf(v[1]) << 16);
        uint32_t hi = (uint32_t)f2bf(v[2]) | ((uint32_t)f2bf(v[3]) << 16);
        int byte = i * 256 + ((2 * j0) ^ ((i & 15) << 4));
        *(uint2*)(SlB + byte) = make_uint2(lo, hi);
      }
    __syncthreads();

    // PV: OT[d][i] += sum_j VT[d][j] * S[i][j]
#pragma unroll
    for (int kc = 0; kc < 4; ++kc) {
      short8 av[4], bv[4];
#pragma unroll
      for (int m2 = 0; m2 < 4; ++m2) {
        int d = wd * 64 + m2 * 16 + l15;
        av[m2] = *(const short8*)(VT + (size_t)(b * Dn + d) * Tn + (size_t)st * 128 + kc * 32 + lg * 8);
      }
#pragma unroll
      for (int n2 = 0; n2 < 4; ++n2) {
        int i = wi2 * 64 + n2 * 16 + l15;
        int j = kc * 32 + lg * 8;
        int byte = i * 256 + ((2 * j) ^ ((i & 15) << 4));
        bv[n2] = *(const short8*)(SlB + byte);
      }
#pragma unroll
      for (int m2 = 0; m2 < 4; ++m2)
#pragma unroll
        for (int n2 = 0; n2 < 4; ++n2)
          oacc[m2][n2] = __builtin_amdgcn_mfma_f32_16x16x32_bf16(av[m2], bv[n2], oacc[m2][n2], 0, 0, 0);
    }
    // next iteration's leading __syncthreads protects Qt/Qs/Sl reuse
  }

  // combine partial O via atomics (O was zeroed by hipMemsetAsync)
  float* Obh = O + ((size_t)bh * Tn + (size_t)tt * 128) * Dn;
#pragma unroll
  for (int m2 = 0; m2 < 4; ++m2)
#pragma unroll
    for (int n2 = 0; n2 < 4; ++n2) {
      int dbase = wd * 64 + m2 * 16 + lg * 4;
      int i = wi2 * 64 + n2 * 16 + l15;
#pragma unroll
      for (int rr = 0; rr < 4; ++rr)
        atomicAdd(Obh + (size_t)i * Dn + dbase + rr, oacc[m2][n2][rr]);
    }
}

extern "C" void kernel_launch(void* const* d_in, const int* in_sizes, int n_in,
                              void* d_out, int out_size, void* d_ws, size_t ws_size,
                              hipStream_t stream) {
  const float* Q = (const float*)d_in[0];
  const float* V = (const float*)d_in[1];
  float* O = (float*)d_out;

  // ws layout: QR bf16 [BH][T][N] (64 MiB) then VT bf16 [B][D][T] (2 MiB)
  uint16_t* QRw = (uint16_t*)d_ws;
  uint16_t* VTw = QRw + (size_t)BH * Tn * Nn;

  hipMemsetAsync(d_out, 0, (size_t)out_size * sizeof(float), stream);
  rope_kernel<<<(BH * (size_t)Tn * Nn / 4) / 256, 256, 0, stream>>>(Q, QRw);
  vt_kernel<<<(Bn * Dn * Tn) / 256, 256, 0, stream>>>(V, VTw);
  attn_kernel<<<BH * JPH, 512, 0, stream>>>(QRw, VTw, O);
}